// Round 7
// baseline (100.251 us; speedup 1.0000x reference)
//
#include <hip/hip_runtime.h>
#include <math.h>

// Adder2D: out[n,co,h,w] = -sum_{ci,kh,kw} |x[n,ci,h+kh-1,w+kw-1] - w[co,ci,kh,kw]|
// x: [16,64,32,32] f32, w: [64,64,3,3] f32, out: [16,64,32,32] f32, pad=1 stride=1.
//
// R9: amortize per-iteration overhead. R8 ledger @47.4us (114k cy/CU):
// VALU ~38k (true ~35%; derived 70% is 2x-inflated), LDS ~23k, ~54k stall.
// Stalls are per-ci overheads (s_load wait, ds_read latency, barriers)
// over only 144 VALU. Now 4 px/thread: block 256 thr = 8 col-quads x 8
// rows x 4 ci-groups (same 32x8x4co tile, same grid 1024). Per thread-ci:
// 288 core VALU per {1 s_load slice + 9 ds_read_b64} -- SMEM waits halve,
// LDS reads/elem -25%, 576cy VALU covers K$ latency. Final store = b128.
// Same LW=34 shifted layout, same repack-w scalar-pipe feed as R8.

#define N_   16
#define CI_  64
#define CO_  64
#define HW_  32
#define CG   4      // co per thread (= all of COB)
#define COB  4      // co per block
#define PX   4      // pixels per thread
#define RG   8      // pixel rows per block
#define CIC  16     // ci planes staged per round
#define CPG  4      // ci planes computed per group per round
#define ROWS (RG + 2)
#define LW   34     // col0 = left halo, 1..32 = data, 33 = right halo
#define WSLICE 64   // floats per (cob,ci) w-slice slot (36 used, 256B aligned)

#define XS_WORDS (CIC * ROWS * LW)        // 5440 words = 21760 B

typedef __attribute__((ext_vector_type(16))) float f16v;
typedef __attribute__((ext_vector_type(4)))  float f4v;

// ---- repack: w[co][ci][t] -> wr[(co/4)*64+ci][ (co&3)*9 + t ], 64-f slots ----
__global__ void repack_w(const float* __restrict__ w, float* __restrict__ wr)
{
    int i  = blockIdx.x * 256 + threadIdx.x;   // 4096 = (co,ci) pairs
    int co = i >> 6;
    int ci = i & 63;
    float* dst = wr + (size_t)((co >> 2) * 64 + ci) * WSLICE + (co & 3) * 9;
    const float* src = w + (size_t)co * (CI_ * 9) + ci * 9;
#pragma unroll
    for (int t = 0; t < 9; ++t) dst[t] = src[t];
}

__device__ __forceinline__ float wget(const f16v& a, const f16v& b, const f4v& c, int idx)
{
    // idx is compile-time after full unroll
    return idx < 16 ? a[idx] : (idx < 32 ? b[idx - 16] : c[idx - 32]);
}

__global__ __launch_bounds__(256, 4) void adder2d_kernel(
    const float* __restrict__ x, const float* __restrict__ wr,
    float* __restrict__ out)
{
    __shared__ __align__(16) float smem[XS_WORDS];
    float (*xs)[ROWS][LW] = (float (*)[ROWS][LW])smem;   // phase A
    float (*red)[64][16]  = (float (*)[64][16])smem;     // phase B: aliases xs
                                                         // 3*64*16 = 3072 <= 5440 ok

    const int tid = threadIdx.x;
    const int u   = tid & 7;             // col-quad: pixels at cols 4u..4u+3
    const int rl  = (tid >> 3) & 7;      // pixel row within block
    const int cig = tid >> 6;            // ci group: 0..3 (uniform per wave)
    const int r0  = blockIdx.x * RG;
    const int co0 = blockIdx.y * COB;
    const int n   = blockIdx.z;

    // wave-uniform ci-group index, provably scalar for the s_load pointer
    const int cigs = __builtin_amdgcn_readfirstlane(cig);
    const float* wrb = wr + (size_t)blockIdx.y * 64 * WSLICE;

    // ---- zero xs once: halo cols (0,33) and OOB row slots stay zero ----
    for (int i = tid; i < XS_WORDS / 4; i += 256)
        ((float4*)smem)[i] = float4{0.f, 0.f, 0.f, 0.f};

    float acc[PX][CG];
#pragma unroll
    for (int i = 0; i < PX; ++i)
#pragma unroll
        for (int j = 0; j < CG; ++j) acc[i][j] = 0.f;

    const float* xn = x + (size_t)n * CI_ * HW_ * HW_;
    const int pbase = cig * CPG;

    for (int round = 0; round < CI_ / CIC; ++round) {
        const int cc0 = round * CIC;
        __syncthreads();   // protect LDS from previous round's readers
        // ---- stage CIC planes, rows r0-1..r0+8: 1280 float4 units, 5/thread ----
        for (int i = tid; i < CIC * ROWS * (HW_ / 4); i += 256) {
            int plane = i / (ROWS * (HW_ / 4));
            int rem   = i - plane * (ROWS * (HW_ / 4));
            int rr    = rem >> 3;
            int f4    = rem & 7;
            int gr    = r0 - 1 + rr;
            if ((unsigned)gr < HW_) {
                float4 v = ((const float4*)(xn + (size_t)(cc0 + plane) * HW_ * HW_
                                            + gr * HW_))[f4];
                float* dst = &xs[plane][rr][1 + 4 * f4];   // data cols start at 1
                dst[0] = v.x; dst[1] = v.y; dst[2] = v.z; dst[3] = v.w;
            }
        }
        __syncthreads();

#pragma unroll
        for (int cil = 0; cil < CPG; ++cil) {
            const int pl  = pbase + cil;             // per-thread (LDS path)
            const int cis = cc0 + cigs * CPG + cil;  // scalar (SMEM path)

            // ---- w slice (36 floats) via scalar loads into SGPRs ----
            const float* p = wrb + (size_t)cis * WSLICE;
            f16v wa, wb2; f4v wc;
            asm volatile(
                "s_load_dwordx16 %0, %3, 0x0\n\t"
                "s_load_dwordx16 %1, %3, 0x40\n\t"
                "s_load_dwordx4  %2, %3, 0x80\n\t"
                "s_waitcnt lgkmcnt(0)"
                : "=s"(wa), "=s"(wb2), "=s"(wc)
                : "s"(p));

            // x patch for 4 pixels: rows rl..rl+2, storage cols 4u..4u+5
            // (= real cols 4u-1..4u+4, halos pre-zeroed). 3 aligned b64/row.
            float xr[3][6];
#pragma unroll
            for (int kh = 0; kh < 3; ++kh) {
                const float* row = &xs[pl][rl + kh][4 * u];
                float2 a = *(const float2*)&row[0];
                float2 b = *(const float2*)&row[2];
                float2 c = *(const float2*)&row[4];
                xr[kh][0] = a.x; xr[kh][1] = a.y;
                xr[kh][2] = b.x; xr[kh][3] = b.y;
                xr[kh][4] = c.x; xr[kh][5] = c.y;
            }

            // 288 VALU: 4 px x 4 co x 9 taps, v_sub(v,s,v) + v_add(abs)
#pragma unroll
            for (int kh = 0; kh < 3; ++kh)
#pragma unroll
                for (int kw = 0; kw < 3; ++kw) {
                    const int t = kh * 3 + kw;
#pragma unroll
                    for (int j = 0; j < CG; ++j) {
                        float wjt = wget(wa, wb2, wc, j * 9 + t);
#pragma unroll
                        for (int i = 0; i < PX; ++i)
                            acc[i][j] += fabsf(xr[kh][i + kw] - wjt);
                    }
                }
        }
    }

    // ---- combine the four ci-group partials (red aliases dead xs) ----
    __syncthreads();   // all xs readers done before overwrite
    if (cig != 0) {
        int t = tid & 63;
#pragma unroll
        for (int i = 0; i < PX; ++i)
            *(float4*)&red[cig - 1][t][4 * i] =
                float4{acc[i][0], acc[i][1], acc[i][2], acc[i][3]};
    }
    __syncthreads();
    if (cig == 0) {
#pragma unroll
        for (int g = 0; g < 3; ++g)
#pragma unroll
            for (int i = 0; i < PX; ++i) {
                float4 r = *(const float4*)&red[g][tid][4 * i];
                acc[i][0] += r.x; acc[i][1] += r.y;
                acc[i][2] += r.z; acc[i][3] += r.w;
            }
        float* op = out + (((size_t)n * CO_ + co0) * HW_ + (r0 + rl)) * HW_ + 4 * u;
#pragma unroll
        for (int j = 0; j < CG; ++j)
            *(float4*)&op[(size_t)j * HW_ * HW_] =
                float4{-acc[0][j], -acc[1][j], -acc[2][j], -acc[3][j]};
    }
}

extern "C" void kernel_launch(void* const* d_in, const int* in_sizes, int n_in,
                              void* d_out, int out_size, void* d_ws, size_t ws_size,
                              hipStream_t stream) {
    const float* x  = (const float*)d_in[0];
    const float* wp = (const float*)d_in[1];
    float* out      = (float*)d_out;
    float* wr       = (float*)d_ws;   // 16*64*64*4 = 256 KiB used

    repack_w<<<dim3(16), 256, 0, stream>>>(wp, wr);
    dim3 grid(HW_ / RG, CO_ / COB, N_);   // (4, 16, 16) = 1024 blocks
    adder2d_kernel<<<grid, 256, 0, stream>>>(x, wr, out);
}